// Round 1
// baseline (4618.000 us; speedup 1.0000x reference)
//
#include <hip/hip_runtime.h>
#include <math.h>

#define GRIDW 32
#define NSRC 1024
#define NPTS 256
#define NIMG 8
#define EPS 0.0025f
#define INV_EPS 400.0f
#define SKIPTH 0.25f
#define NITER 100
// EPS * (-log(256))
#define EPS_LB (-0.013862943611198906f)

// online log-sum-exp in "t units" (t = eps * arg). Skips exp when the term
// provably underflows relative to the running max (e^-100 < fp32 denormal dust).
__device__ __forceinline__ void lse_add(float& m, float& s, float t) {
  if (t > m - SKIPTH) {
    float mn = fmaxf(m, t);
    s = s * __expf((m - mn) * INV_EPS) + __expf((t - mn) * INV_EPS);
    m = mn;
  }
}

__device__ __forceinline__ void lse_merge(float& m, float& s, float mo, float so) {
  float mn = fmaxf(m, mo);
  if (mn == -INFINITY) return;  // both empty
  s = s * __expf((m - mn) * INV_EPS) + so * __expf((mo - mn) * INV_EPS);
  m = mn;
}

__device__ float block_sum(float v, float* red) {
  #pragma unroll
  for (int off = 32; off; off >>= 1) v += __shfl_xor(v, off, 64);
  __syncthreads();
  if ((threadIdx.x & 63) == 0) red[threadIdx.x >> 6] = v;
  __syncthreads();
  if (threadIdx.x == 0) {
    float t = 0.0f;
    #pragma unroll
    for (int k = 0; k < 16; ++k) t += red[k];
    v = t;
  }
  return v;
}

__global__ __launch_bounds__(1024)
void ot_sinkhorn(const float* __restrict__ dens_all,
                 const float* __restrict__ pts_all,
                 float* __restrict__ partials)
{
  __shared__ __align__(16) float F_s[NSRC];   // eps*la + f (source-side)
  __shared__ __align__(16) float G_s[NSRC];   // eps*lb + g (target-side)
  __shared__ __align__(16) float la_s[NSRC];
  __shared__ __align__(16) float A_s[NSRC];
  __shared__ __align__(16) float T_s[NSRC];   // separable intermediate (aa)
  __shared__ __align__(16) float px_s[NPTS];
  __shared__ __align__(16) float py_s[NPTS];
  __shared__ float red_s[16];

  const int tid = threadIdx.x;
  const int prob = blockIdx.x;
  const int img = prob / 3;
  const int type = prob - img * 3;
  const float* dens = dens_all + img * NSRC;
  const float* pts = pts_all + img * (NPTS * 2);

  float acc = 0.0f;

  if (type == 0) {
    // ================= ot_ab : grid (weights a=dens) -> points (b uniform) ====
    {
      float a = dens[tid];
      A_s[tid] = a;
      float la = (a > 0.0f) ? __logf(a) : -1e30f;
      la_s[tid] = la;
      F_s[tid] = EPS * la;                 // f = 0
      if (tid < NPTS) { px_s[tid] = pts[2 * tid]; py_s[tid] = pts[2 * tid + 1]; }
    }
    __syncthreads();

    const int j = tid >> 2, ch = tid & 3;  // 4 threads per target point j
    const float pxj = px_s[j];
    const float pyj = py_s[j];
    const float c0 = (float)((tid & 31) * 8 + 4);  // this thread's grid point (f-update)
    const float c1 = (float)((tid >> 5) * 8 + 4);

    for (int it = 0; it <= NITER; ++it) {
      // ---- g-update: g[j] = -(max + eps*log(sum)) over 1024 grid cells
      float m = -INFINITY, s = 0.0f;
      #pragma unroll 1
      for (int r = ch * 8; r < ch * 8 + 8; ++r) {
        float dy = (float)(r * 8 + 4) - pyj;
        float rowbase = -0.5f * dy * dy;
        const float4* Frow = (const float4*)(F_s + r * GRIDW);
        float dx = 4.0f - pxj;
        #pragma unroll
        for (int q4 = 0; q4 < 8; ++q4) {
          float4 Fv = Frow[q4];
          { float t = fmaf(dx, dx * -0.5f, Fv.x + rowbase); lse_add(m, s, t); dx += 8.0f; }
          { float t = fmaf(dx, dx * -0.5f, Fv.y + rowbase); lse_add(m, s, t); dx += 8.0f; }
          { float t = fmaf(dx, dx * -0.5f, Fv.z + rowbase); lse_add(m, s, t); dx += 8.0f; }
          { float t = fmaf(dx, dx * -0.5f, Fv.w + rowbase); lse_add(m, s, t); dx += 8.0f; }
        }
      }
      #pragma unroll
      for (int off = 1; off < 4; off <<= 1) {
        float mo = __shfl_xor(m, off, 64);
        float so = __shfl_xor(s, off, 64);
        lse_merge(m, s, mo, so);
      }
      float g = -(m + EPS * __logf(s));

      if (it == NITER) {                    // final extrapolated g
        if (ch == 0) acc += g * (1.0f / NPTS);
        break;
      }
      if (ch == 0) G_s[j] = g + EPS_LB;
      __syncthreads();

      // ---- f-update: each thread owns one grid point, reduce over 256 points
      float mf = -INFINITY, sf = 0.0f;
      #pragma unroll 1
      for (int jj = 0; jj < NPTS; jj += 4) {
        float4 pxv = *(const float4*)(px_s + jj);
        float4 pyv = *(const float4*)(py_s + jj);
        float4 Gv  = *(const float4*)(G_s + jj);
        { float dx = c0 - pxv.x, dv = c1 - pyv.x; float u = fmaf(dv, dv, dx * dx); lse_add(mf, sf, fmaf(u, -0.5f, Gv.x)); }
        { float dx = c0 - pxv.y, dv = c1 - pyv.y; float u = fmaf(dv, dv, dx * dx); lse_add(mf, sf, fmaf(u, -0.5f, Gv.y)); }
        { float dx = c0 - pxv.z, dv = c1 - pyv.z; float u = fmaf(dv, dv, dx * dx); lse_add(mf, sf, fmaf(u, -0.5f, Gv.z)); }
        { float dx = c0 - pxv.w, dv = c1 - pyv.w; float u = fmaf(dv, dv, dx * dx); lse_add(mf, sf, fmaf(u, -0.5f, Gv.w)); }
      }
      float f = -(mf + EPS * __logf(sf));
      F_s[tid] = fmaf(EPS, la_s[tid], f);
      __syncthreads();
    }
    {
      float a = A_s[tid];
      if (a > 0.0f) acc += a * (F_s[tid] - EPS * la_s[tid]);
    }
  } else if (type == 1) {
    // ================= ot_aa : grid -> grid (a=b=dens), separable LSE ========
    {
      float a = dens[tid];
      A_s[tid] = a;
      float la = (a > 0.0f) ? __logf(a) : -1e30f;
      la_s[tid] = la;
      F_s[tid] = EPS * la;
    }
    __syncthreads();

    const int q1 = tid & 31, r1 = tid >> 5;  // pass1: source column q1, target row r1
    const int r2 = tid & 31, q2 = tid >> 5;  // pass2: output (q'=q2, r'=r2)
    const int np = r2 * GRIDW + q2;

    for (int it = 0; it <= NITER; ++it) {
      // ---- g-update = U(F_s): pass1 over y, pass2 over x
      {
        float m = -INFINITY, s = 0.0f;
        float df = (float)(-r1);
        #pragma unroll 1
        for (int r = 0; r < GRIDW; ++r) {
          float t = fmaf(df * df, -32.0f, F_s[r * GRIDW + q1]);  // 0.5*(8*d)^2 = 32 d^2
          lse_add(m, s, t);
          df += 1.0f;
        }
        T_s[q1 * GRIDW + r1] = m + EPS * __logf(s);
      }
      __syncthreads();
      float pot;
      {
        float m = -INFINITY, s = 0.0f;
        float dq = (float)(-q2);
        #pragma unroll 1
        for (int qi = 0; qi < GRIDW; ++qi) {
          float t = fmaf(dq * dq, -32.0f, T_s[qi * GRIDW + r2]);
          lse_add(m, s, t);
          dq += 1.0f;
        }
        pot = -(m + EPS * __logf(s));
      }
      if (it == NITER) { acc += A_s[np] * pot; break; }
      G_s[np] = fmaf(EPS, la_s[np], pot);
      __syncthreads();

      // ---- f-update = U(G_s)
      {
        float m = -INFINITY, s = 0.0f;
        float df = (float)(-r1);
        #pragma unroll 1
        for (int r = 0; r < GRIDW; ++r) {
          float t = fmaf(df * df, -32.0f, G_s[r * GRIDW + q1]);
          lse_add(m, s, t);
          df += 1.0f;
        }
        T_s[q1 * GRIDW + r1] = m + EPS * __logf(s);
      }
      __syncthreads();
      {
        float m = -INFINITY, s = 0.0f;
        float dq = (float)(-q2);
        #pragma unroll 1
        for (int qi = 0; qi < GRIDW; ++qi) {
          float t = fmaf(dq * dq, -32.0f, T_s[qi * GRIDW + r2]);
          lse_add(m, s, t);
          dq += 1.0f;
        }
        pot = -(m + EPS * __logf(s));
      }
      __syncthreads();
      F_s[np] = fmaf(EPS, la_s[np], pot);
      __syncthreads();
    }
    {
      float a = A_s[tid];
      if (a > 0.0f) acc += a * (F_s[tid] - EPS * la_s[tid]);
    }
  } else {
    // ================= ot_bb : points -> points (a=b uniform) ================
    if (tid < NPTS) {
      px_s[tid] = pts[2 * tid];
      py_s[tid] = pts[2 * tid + 1];
      F_s[tid] = EPS_LB;                   // f = 0
    }
    __syncthreads();
    const int j = tid >> 2, ch = tid & 3;
    const float qx = px_s[j], qy = py_s[j];

    for (int it = 0; it <= NITER; ++it) {
      // ---- g-update from F_s
      float m = -INFINITY, s = 0.0f;
      #pragma unroll 1
      for (int i = ch * 64; i < ch * 64 + 64; i += 4) {
        float4 pxv = *(const float4*)(px_s + i);
        float4 pyv = *(const float4*)(py_s + i);
        float4 Fv  = *(const float4*)(F_s + i);
        { float dx = pxv.x - qx, dv = pyv.x - qy; float u = fmaf(dv, dv, dx * dx); lse_add(m, s, fmaf(u, -0.5f, Fv.x)); }
        { float dx = pxv.y - qx, dv = pyv.y - qy; float u = fmaf(dv, dv, dx * dx); lse_add(m, s, fmaf(u, -0.5f, Fv.y)); }
        { float dx = pxv.z - qx, dv = pyv.z - qy; float u = fmaf(dv, dv, dx * dx); lse_add(m, s, fmaf(u, -0.5f, Fv.z)); }
        { float dx = pxv.w - qx, dv = pyv.w - qy; float u = fmaf(dv, dv, dx * dx); lse_add(m, s, fmaf(u, -0.5f, Fv.w)); }
      }
      #pragma unroll
      for (int off = 1; off < 4; off <<= 1) {
        float mo = __shfl_xor(m, off, 64);
        float so = __shfl_xor(s, off, 64);
        lse_merge(m, s, mo, so);
      }
      float g = -(m + EPS * __logf(s));
      if (it == NITER) {
        if (ch == 0) acc += g * (1.0f / NPTS);
        break;
      }
      if (ch == 0) G_s[j] = g + EPS_LB;
      __syncthreads();

      // ---- f-update from G_s (same point set, symmetric)
      float m2 = -INFINITY, s2 = 0.0f;
      #pragma unroll 1
      for (int i = ch * 64; i < ch * 64 + 64; i += 4) {
        float4 pxv = *(const float4*)(px_s + i);
        float4 pyv = *(const float4*)(py_s + i);
        float4 Gv  = *(const float4*)(G_s + i);
        { float dx = pxv.x - qx, dv = pyv.x - qy; float u = fmaf(dv, dv, dx * dx); lse_add(m2, s2, fmaf(u, -0.5f, Gv.x)); }
        { float dx = pxv.y - qx, dv = pyv.y - qy; float u = fmaf(dv, dv, dx * dx); lse_add(m2, s2, fmaf(u, -0.5f, Gv.y)); }
        { float dx = pxv.z - qx, dv = pyv.z - qy; float u = fmaf(dv, dv, dx * dx); lse_add(m2, s2, fmaf(u, -0.5f, Gv.z)); }
        { float dx = pxv.w - qx, dv = pyv.w - qy; float u = fmaf(dv, dv, dx * dx); lse_add(m2, s2, fmaf(u, -0.5f, Gv.w)); }
      }
      #pragma unroll
      for (int off = 1; off < 4; off <<= 1) {
        float mo = __shfl_xor(m2, off, 64);
        float so = __shfl_xor(s2, off, 64);
        lse_merge(m2, s2, mo, so);
      }
      float f = -(m2 + EPS * __logf(s2));
      if (ch == 0) F_s[j] = f + EPS_LB;
      __syncthreads();
    }
    if (tid < NPTS) acc += (F_s[tid] - EPS_LB) * (1.0f / NPTS);
  }

  float total = block_sum(acc, red_s);
  if (tid == 0) partials[prob] = total;
}

__global__ void ot_finalize(const float* __restrict__ partials, float* __restrict__ out) {
  if (threadIdx.x == 0 && blockIdx.x == 0) {
    float t = 0.0f;
    #pragma unroll
    for (int i = 0; i < NIMG; ++i)
      t += partials[3 * i] - 0.5f * (partials[3 * i + 1] + partials[3 * i + 2]);
    out[0] = t;
  }
}

extern "C" void kernel_launch(void* const* d_in, const int* in_sizes, int n_in,
                              void* d_out, int out_size, void* d_ws, size_t ws_size,
                              hipStream_t stream) {
  const float* dens = (const float*)d_in[0];   // (8,1,32,32) f32
  const float* pts  = (const float*)d_in[1];   // (8,256,2)   f32
  float* partials = (float*)d_ws;              // 24 floats
  ot_sinkhorn<<<dim3(NIMG * 3), dim3(1024), 0, stream>>>(dens, pts, partials);
  ot_finalize<<<dim3(1), dim3(64), 0, stream>>>(partials, (float*)d_out);
}

// Round 3
// 1030.082 us; speedup vs baseline: 4.4831x; 4.4831x over previous
//
#include <hip/hip_runtime.h>
#include <math.h>

#define NIMG 8
#define NSRC 1024
#define NPTS 256
#define NITER 100
#define KCONV 577.0780163555854f        // log2(e)/eps
#define INV_KC 0.0017328679513998632f   // eps*ln2
#define EPS_LBC (-0.013862943611198906f) // eps*ln(1/256)
#define EPSQ 0.0025f
#define NEG_BIG (-1e30f)

#define AB_K 16
#define BB_K 8
#define NBAR 256
// ws layout (float words)
#define WS_PART 4096
#define WS_FC 4352
#define WS_GC 12544
#define WS_BF 14592
#define WS_BG 16640
#define WS_MEMSET_WORDS 4352

#define EXP2F(x) __builtin_amdgcn_exp2f(x)
#define LOG2F(x) __builtin_amdgcn_logf(x)

#define F4E(v,e) ((e)==0?(v).x:(e)==1?(v).y:(e)==2?(v).z:(v).w)

__device__ __forceinline__ void gbar(unsigned int* ctr, unsigned int want) {
  __syncthreads();
  if (threadIdx.x == 0) {
    __hip_atomic_fetch_add(ctr, 1u, __ATOMIC_RELEASE, __HIP_MEMORY_SCOPE_AGENT);
    while (__hip_atomic_load(ctr, __ATOMIC_RELAXED, __HIP_MEMORY_SCOPE_AGENT) < want)
      __builtin_amdgcn_s_sleep(2);
    (void)__hip_atomic_load(ctr, __ATOMIC_ACQUIRE, __HIP_MEMORY_SCOPE_AGENT);
  }
  __syncthreads();
}

__global__ __launch_bounds__(1024)
void ot_sinkhorn(const float* __restrict__ dens_all,
                 const float* __restrict__ pts_all,
                 float* __restrict__ ws)
{
  __shared__ __align__(16) float FcL[32 * 36];   // padded F tile (ab g-half)
  __shared__ __align__(16) float GcL[16 * 20];   // padded G source (ab f-half)
  __shared__ __align__(16) float AL[32 * 12];    // padded bb potentials
  __shared__ __align__(16) float pxL[NPTS];
  __shared__ __align__(16) float pyL[NPTS];
  __shared__ __align__(16) float epslaL[NSRC];
  __shared__ __align__(16) float aL[NSRC];
  __shared__ __align__(16) float FaL[NSRC];      // aa potentials
  __shared__ __align__(16) float TaL[33 * 32];   // aa separable intermediate
  __shared__ float red[16];

  const int tid = threadIdx.x;
  const int bid = blockIdx.x;
  const int img = bid & 7;
  const float* dens = dens_all + img * NSRC;
  const float* pts = pts_all + img * (NPTS * 2);
  unsigned int* bar = (unsigned int*)ws;
  float* partials = ws + WS_PART;

  float acc = 0.0f;

  if (bid < 128) {
    // ======================= ot_ab, split across AB_K=16 blocks =======================
    const int sub = bid >> 3;            // 0..15
    float* Fcbuf = ws + WS_FC + img * NSRC;
    float* Gcbuf = ws + WS_GC + img * NPTS;
    unsigned int* ctr = bar + img * NBAR;

    {
      float a = dens[tid];
      aL[tid] = a;
      float ela = (a > 0.0f) ? EPSQ * __logf(a) : NEG_BIG;
      epslaL[tid] = ela;
      FcL[(tid >> 5) * 36 + (tid & 31)] = ela;   // f = 0
      if (tid < NPTS) { pxL[tid] = pts[2 * tid]; pyL[tid] = pts[2 * tid + 1]; }
    }
    __syncthreads();

    // g-half geometry: one wave per target
    const int wv = tid >> 6, lane = tid & 63;
    const int r = lane & 31, h = lane >> 5;
    const int j = sub * 16 + wv;
    const float pxj = pxL[j], pyj = pyL[j];
    const float dyv = (float)(r * 8 + 4) - pyj;
    const float dy2 = dyv * dyv;
    const float px0 = (float)(h * 128 + 4) - pxj;

    // f-half geometry: 64 cells/block, 16 threads/cell
    const int cl = tid >> 4, ch = tid & 15;
    const int c = sub * 64 + cl;
    const float cxi = (float)((c & 31) * 8 + 4);
    const float cyi = (float)((c >> 5) * 8 + 4);
    const float epsla_c = epslaL[c];
    const float a_c = aL[c];
    float4 px4[4], py4[4];
    #pragma unroll
    for (int k = 0; k < 4; ++k) {
      px4[k] = *(const float4*)(pxL + ch * 16 + k * 4);
      py4[k] = *(const float4*)(pyL + ch * 16 + k * 4);
    }
    const float4* FcL4 = (const float4*)FcL;
    const float4* GcL4 = (const float4*)GcL;

    for (int it = 0;; ++it) {
      if (it) FcL[(tid >> 5) * 36 + (tid & 31)] = Fcbuf[tid];
      __syncthreads();

      // ---- g-half: two-pass LSE over 1024 cells for this wave's target ----
      float tt[16];
      float m = -INFINITY;
      #pragma unroll
      for (int k = 0; k < 4; ++k) {
        float4 Fv = FcL4[r * 9 + h * 4 + k];
        #pragma unroll
        for (int e = 0; e < 4; ++e) {
          float dx = px0 + (float)(k * 32 + e * 8);
          float t = fmaf(fmaf(dx, dx, dy2), -0.5f, F4E(Fv, e));
          tt[k * 4 + e] = t;
          m = fmaxf(m, t);
        }
      }
      #pragma unroll
      for (int o = 1; o < 64; o <<= 1) m = fmaxf(m, __shfl_xor(m, o, 64));
      float s = 0.0f;
      #pragma unroll
      for (int i = 0; i < 16; ++i) s += EXP2F((tt[i] - m) * KCONV);
      #pragma unroll
      for (int o = 1; o < 64; o <<= 1) s += __shfl_xor(s, o, 64);
      float g = -(m + LOG2F(s) * INV_KC);

      if (it == NITER) { if (lane == 0) acc += g * (1.0f / 256.0f); break; }
      if (lane == 0) Gcbuf[j] = g + EPS_LBC;
      gbar(ctr + 2 * it, AB_K);

      if (tid < NPTS) GcL[(tid >> 4) * 20 + (tid & 15)] = Gcbuf[tid];
      __syncthreads();

      // ---- f-half: two-pass LSE over 256 targets for this thread-group's cell ----
      float4 G4[4];
      #pragma unroll
      for (int k = 0; k < 4; ++k) G4[k] = GcL4[ch * 5 + k];
      float mf = -INFINITY;
      #pragma unroll
      for (int k = 0; k < 4; ++k) {
        #pragma unroll
        for (int e = 0; e < 4; ++e) {
          float dx = F4E(px4[k], e) - cxi;
          float dyq = F4E(py4[k], e) - cyi;
          float u = fmaf(dyq, dyq, dx * dx);
          float t = fmaf(u, -0.5f, F4E(G4[k], e));
          tt[k * 4 + e] = t;
          mf = fmaxf(mf, t);
        }
      }
      #pragma unroll
      for (int o = 1; o < 16; o <<= 1) mf = fmaxf(mf, __shfl_xor(mf, o, 64));
      float sf = 0.0f;
      #pragma unroll
      for (int i = 0; i < 16; ++i) sf += EXP2F((tt[i] - mf) * KCONV);
      #pragma unroll
      for (int o = 1; o < 16; o <<= 1) sf += __shfl_xor(sf, o, 64);
      float f = -(mf + LOG2F(sf) * INV_KC);
      if (ch == 0) {
        Fcbuf[c] = f + epsla_c;
        if (it == NITER - 1) acc += a_c * f;
      }
      gbar(ctr + 2 * it + 1, AB_K);
    }
    // partial slot
    {
      #pragma unroll
      for (int o = 32; o; o >>= 1) acc += __shfl_xor(acc, o, 64);
      __syncthreads();
      if ((tid & 63) == 0) red[tid >> 6] = acc;
      __syncthreads();
      if (tid == 0) {
        float t = 0.0f;
        #pragma unroll
        for (int k = 0; k < 16; ++k) t += red[k];
        partials[img * 16 + sub] = t;
      }
    }
  } else if (bid < 192) {
    // ======================= ot_bb, split across BB_K=8 blocks =======================
    const int sub = (bid - 128) >> 3;    // 0..7
    float* bbF = ws + WS_BF + img * NPTS;
    float* bbG = ws + WS_BG + img * NPTS;
    unsigned int* ctr = bar + (8 + img) * NBAR;

    if (tid < NPTS) { pxL[tid] = pts[2 * tid]; pyL[tid] = pts[2 * tid + 1]; }
    __syncthreads();

    const int wv = tid >> 5, lane32 = tid & 31;
    const int j = sub * 32 + wv;
    const float pxj = pxL[j], pyj = pyL[j];
    float4 spx[2], spy[2];
    spx[0] = *(const float4*)(pxL + lane32 * 8);
    spx[1] = *(const float4*)(pxL + lane32 * 8 + 4);
    spy[0] = *(const float4*)(pyL + lane32 * 8);
    spy[1] = *(const float4*)(pyL + lane32 * 8 + 4);
    const float4* AL4 = (const float4*)AL;

    for (int it = 0;; ++it) {
      if (tid < NPTS) AL[(tid >> 3) * 12 + (tid & 7)] = it ? bbF[tid] : EPS_LBC;
      __syncthreads();

      // ---- g-half ----
      float4 A0 = AL4[lane32 * 3 + 0], A1 = AL4[lane32 * 3 + 1];
      float tt[8];
      float m = -INFINITY;
      #pragma unroll
      for (int k = 0; k < 8; ++k) {
        float4 pk = spx[k >> 2], qk = spy[k >> 2];
        float4 Ak = (k < 4) ? A0 : A1;
        float dx = F4E(pk, k & 3) - pxj;
        float dyq = F4E(qk, k & 3) - pyj;
        float u = fmaf(dyq, dyq, dx * dx);
        float t = fmaf(u, -0.5f, F4E(Ak, k & 3));
        tt[k] = t;
        m = fmaxf(m, t);
      }
      #pragma unroll
      for (int o = 1; o < 32; o <<= 1) m = fmaxf(m, __shfl_xor(m, o, 64));
      float s = 0.0f;
      #pragma unroll
      for (int k = 0; k < 8; ++k) s += EXP2F((tt[k] - m) * KCONV);
      #pragma unroll
      for (int o = 1; o < 32; o <<= 1) s += __shfl_xor(s, o, 64);
      float g = -(m + LOG2F(s) * INV_KC);

      if (it == NITER) { if (lane32 == 0) acc += g * (1.0f / 256.0f); break; }
      if (lane32 == 0) bbG[j] = g + EPS_LBC;
      gbar(ctr + 2 * it, BB_K);

      if (tid < NPTS) AL[(tid >> 3) * 12 + (tid & 7)] = bbG[tid];
      __syncthreads();

      // ---- f-half (same point set, symmetric) ----
      A0 = AL4[lane32 * 3 + 0]; A1 = AL4[lane32 * 3 + 1];
      float mf = -INFINITY;
      #pragma unroll
      for (int k = 0; k < 8; ++k) {
        float4 pk = spx[k >> 2], qk = spy[k >> 2];
        float4 Ak = (k < 4) ? A0 : A1;
        float dx = F4E(pk, k & 3) - pxj;
        float dyq = F4E(qk, k & 3) - pyj;
        float u = fmaf(dyq, dyq, dx * dx);
        float t = fmaf(u, -0.5f, F4E(Ak, k & 3));
        tt[k] = t;
        mf = fmaxf(mf, t);
      }
      #pragma unroll
      for (int o = 1; o < 32; o <<= 1) mf = fmaxf(mf, __shfl_xor(mf, o, 64));
      float sf = 0.0f;
      #pragma unroll
      for (int k = 0; k < 8; ++k) sf += EXP2F((tt[k] - mf) * KCONV);
      #pragma unroll
      for (int o = 1; o < 32; o <<= 1) sf += __shfl_xor(sf, o, 64);
      float f = -(mf + LOG2F(sf) * INV_KC);
      if (lane32 == 0) {
        bbF[j] = f + EPS_LBC;
        if (it == NITER - 1) acc += f * (1.0f / 256.0f);
      }
      gbar(ctr + 2 * it + 1, BB_K);
    }
    {
      #pragma unroll
      for (int o = 32; o; o >>= 1) acc += __shfl_xor(acc, o, 64);
      __syncthreads();
      if ((tid & 63) == 0) red[tid >> 6] = acc;
      __syncthreads();
      if (tid == 0) {
        float t = 0.0f;
        #pragma unroll
        for (int k = 0; k < 16; ++k) t += red[k];
        partials[128 + img * 8 + sub] = t;
      }
    }
  } else {
    // ======================= ot_aa: single block, separable LSE =======================
    {
      float a = dens[tid];
      aL[tid] = a;
      float ela = (a > 0.0f) ? EPSQ * __logf(a) : NEG_BIG;
      epslaL[tid] = ela;
      FaL[tid] = ela;                    // f = 0, cost units
    }
    __syncthreads();

    const int q1 = tid & 31, r1 = tid >> 5;
    const float r1f = (float)r1;
    const int r2 = tid & 31, q2 = tid >> 5;
    const float q2f = (float)q2;
    const int np = r2 * 32 + q2;
    const float a_np = aL[np];
    const float ela_np = epslaL[np];

    float t[32];
    for (int it = 0;; ++it) {
      // ============ g-half ============
      {
        float m = -INFINITY;
        #pragma unroll
        for (int rr = 0; rr < 32; ++rr) {
          float d = (float)rr - r1f;
          float v = fmaf(d * d, -32.0f, FaL[rr * 32 + q1]);
          t[rr] = v; m = fmaxf(m, v);
        }
        float s = 0.0f;
        #pragma unroll
        for (int rr = 0; rr < 32; ++rr) s += EXP2F((t[rr] - m) * KCONV);
        TaL[q1 * 33 + r1] = m + LOG2F(s) * INV_KC;
      }
      __syncthreads();
      float pot;
      {
        float m = -INFINITY;
        #pragma unroll
        for (int qi = 0; qi < 32; ++qi) {
          float d = (float)qi - q2f;
          float v = fmaf(d * d, -32.0f, TaL[qi * 33 + r2]);
          t[qi] = v; m = fmaxf(m, v);
        }
        float s = 0.0f;
        #pragma unroll
        for (int qi = 0; qi < 32; ++qi) s += EXP2F((t[qi] - m) * KCONV);
        pot = -(m + LOG2F(s) * INV_KC);
      }
      if (it == NITER) { acc += a_np * pot; break; }
      FaL[np] = pot + ela_np;            // G side, weights = a
      __syncthreads();

      // ============ f-half ============
      {
        float m = -INFINITY;
        #pragma unroll
        for (int rr = 0; rr < 32; ++rr) {
          float d = (float)rr - r1f;
          float v = fmaf(d * d, -32.0f, FaL[rr * 32 + q1]);
          t[rr] = v; m = fmaxf(m, v);
        }
        float s = 0.0f;
        #pragma unroll
        for (int rr = 0; rr < 32; ++rr) s += EXP2F((t[rr] - m) * KCONV);
        TaL[q1 * 33 + r1] = m + LOG2F(s) * INV_KC;
      }
      __syncthreads();
      {
        float m = -INFINITY;
        #pragma unroll
        for (int qi = 0; qi < 32; ++qi) {
          float d = (float)qi - q2f;
          float v = fmaf(d * d, -32.0f, TaL[qi * 33 + r2]);
          t[qi] = v; m = fmaxf(m, v);
        }
        float s = 0.0f;
        #pragma unroll
        for (int qi = 0; qi < 32; ++qi) s += EXP2F((t[qi] - m) * KCONV);
        pot = -(m + LOG2F(s) * INV_KC);
      }
      if (it == NITER - 1) acc += a_np * pot;
      FaL[np] = pot + ela_np;
      __syncthreads();
    }
    {
      #pragma unroll
      for (int o = 32; o; o >>= 1) acc += __shfl_xor(acc, o, 64);
      __syncthreads();
      if ((tid & 63) == 0) red[tid >> 6] = acc;
      __syncthreads();
      if (tid == 0) {
        float tsum = 0.0f;
        #pragma unroll
        for (int k = 0; k < 16; ++k) tsum += red[k];
        partials[192 + img] = tsum;
      }
    }
  }
}

__global__ void ot_finalize(const float* __restrict__ partials, float* __restrict__ out) {
  __shared__ float red[4];
  const int tid = threadIdx.x;
  float v = 0.0f;
  if (tid < 200) {
    float w = (tid < 128) ? 1.0f : -0.5f;
    v = w * partials[tid];
  }
  #pragma unroll
  for (int o = 32; o; o >>= 1) v += __shfl_xor(v, o, 64);
  if ((tid & 63) == 0) red[tid >> 6] = v;
  __syncthreads();
  if (tid == 0) out[0] = red[0] + red[1] + red[2] + red[3];
}

extern "C" void kernel_launch(void* const* d_in, const int* in_sizes, int n_in,
                              void* d_out, int out_size, void* d_ws, size_t ws_size,
                              hipStream_t stream) {
  const float* dens = (const float*)d_in[0];   // (8,1,32,32) f32
  const float* pts  = (const float*)d_in[1];   // (8,256,2)   f32
  float* ws = (float*)d_ws;
  (void)hipMemsetAsync(d_ws, 0, WS_MEMSET_WORDS * sizeof(float), stream);  // barriers + partials
  ot_sinkhorn<<<dim3(200), dim3(1024), 0, stream>>>(dens, pts, ws);
  ot_finalize<<<dim3(1), dim3(256), 0, stream>>>(ws + WS_PART, (float*)d_out);
}